// Round 7
// baseline (95.367 us; speedup 1.0000x reference)
//
#include <hip/hip_runtime.h>

// EquivariantGNN: 256 graphs, N=64 nodes, HID=64, fp32 in/out.
// R7: occupancy. R6 was latency-bound at 2 waves/SIMD (142KB LDS -> 1 blk/CU).
// Drop precompute staging (read weights straight from global/L2 in the
// precompute GEMMs) + overlay sHt with sTr/sDsq -> ~64KB LDS -> 2 blk/CU
// -> 4 waves/SIMD. Main-loop structure unchanged from R6.

#define NG 256

typedef __attribute__((ext_vector_type(4))) float f32x4;
typedef __attribute__((ext_vector_type(8))) __bf16 bf16x8;

__device__ __forceinline__ f32x4 mfma16(bf16x8 a, bf16x8 b, f32x4 c){
  return __builtin_amdgcn_mfma_f32_16x16x32_bf16(a, b, c, 0, 0, 0);
}

__device__ __forceinline__ void fma4x4(float* acc, float4 a, float4 b){
  acc[0]  += a.x*b.x; acc[1]  += a.x*b.y; acc[2]  += a.x*b.z; acc[3]  += a.x*b.w;
  acc[4]  += a.y*b.x; acc[5]  += a.y*b.y; acc[6]  += a.y*b.z; acc[7]  += a.y*b.w;
  acc[8]  += a.z*b.x; acc[9]  += a.z*b.y; acc[10] += a.z*b.z; acc[11] += a.z*b.w;
  acc[12] += a.w*b.x; acc[13] += a.w*b.y; acc[14] += a.w*b.z; acc[15] += a.w*b.w;
}

__global__ __launch_bounds__(512)
void egnn_edge_mfma(const float* __restrict__ x,
    const float* __restrict__ emb_w,  const float* __restrict__ emb_b,
    const float* __restrict__ edge_w1,const float* __restrict__ edge_b1,
    const float* __restrict__ edge_w2,const float* __restrict__ edge_b2,
    const float* __restrict__ coord_w1,const float* __restrict__ coord_b1,
    const float* __restrict__ coord_w2,
    float* __restrict__ out, float* __restrict__ ws_mi)
{
  // persistent
  __shared__ __align__(16) float  sAB [64*64];   // a_i[k]+b1[k], f32 [i][k]
  __shared__ __align__(16) __bf16 sC  [64*72];   // c_j[k] bf16 [j][72]
  __shared__ __align__(16) __bf16 sW3t[64*72];   // (W2@cw1)^T [n'][k]
  __shared__ __align__(16) __bf16 sW2t[64*72];   // W2^T [n][k]
  // union region: precompute h^T (16KB f32)  |  main loop Trow(9.2KB)+Dsq(2KB)
  __shared__ __align__(16) unsigned char uniRaw[16384];
  __shared__ float sPX[64], sPY[64], sPZ[64];
  __shared__ __align__(16) float sW1L[64];
  __shared__ float sCB1p[64], sCW2[64], sB2[64], sB1[64];
  __shared__ float sXL[384], sEW[384], sEB[64];

  float*  sHt  = (float*)uniRaw;            // [m][j] 64x64 f32 (precompute)
  __bf16* sTr  = (__bf16*)uniRaw;           // [i][72] bf16 (main)
  float*  sDsq = (float*)(uniRaw + 9216);   // [8][64] f32 (main)

  const int bs  = blockIdx.x, tid = threadIdx.x;
  const int lane = tid & 63, wv = tid >> 6;
  const float* xg = x + bs*384;

  // ---- stage small inputs ----
  if (tid < 384){ sXL[tid] = xg[tid]; sEW[tid] = emb_w[tid]; }
  if (tid < 64){
    sEB[tid] = emb_b[tid];  sB1[tid] = edge_b1[tid]; sB2[tid] = edge_b2[tid];
    sCW2[tid] = coord_w2[tid]; sW1L[tid] = edge_w1[128*64 + tid];
  } else if (tid < 128){
    int j = tid-64; sPX[j]=xg[j*6]; sPY[j]=xg[j*6+1]; sPZ[j]=xg[j*6+2];
  }
  __syncthreads();

  // ---- phase 1: h^T (LDS) + W3 = W2@cw1 (global reads) + W2t + cb1' ----
  #pragma unroll
  for (int e=0;e<8;e++){
    int idx=tid+e*512; int m=idx>>6, j=idx&63;
    float v = sEB[m];
    #pragma unroll
    for (int d=0; d<6; d++) v += sXL[j*6+d]*sEW[d*64+m];
    sHt[m*64+j] = v;
  }
  { // W3^T: thread (k=tid>>3, 8 cols at c0=(tid&7)*8)
    int k = tid>>3, c0 = (tid&7)*8;
    float a8[8] = {};
    for (int n=0;n<64;n++){
      float w = edge_w2[k*64+n];
      float4 b0 = *(const float4*)&coord_w1[n*64+c0];
      float4 b1 = *(const float4*)&coord_w1[n*64+c0+4];
      a8[0]+=w*b0.x; a8[1]+=w*b0.y; a8[2]+=w*b0.z; a8[3]+=w*b0.w;
      a8[4]+=w*b1.x; a8[5]+=w*b1.y; a8[6]+=w*b1.z; a8[7]+=w*b1.w;
    }
    #pragma unroll
    for (int cc=0;cc<8;cc++) sW3t[(c0+cc)*72 + k] = (__bf16)a8[cc];
  }
  #pragma unroll
  for (int e=0;e<8;e++){ int idx=tid+e*512; int n=idx>>6, k=idx&63;
    sW2t[n*72+k] = (__bf16)edge_w2[k*64+n]; }
  if (tid < 64){
    float s = coord_b1[tid];
    for (int n=0;n<64;n++) s += sB2[n]*coord_w1[n*64+tid];
    sCB1p[tid] = s;
  }
  __syncthreads();

  // ---- phase 2: a+b1 -> sAB (group0), c -> sC bf16 (group1); W1 from global ----
  {
    const int g = tid>>8, tl = tid&255, tjx = tl>>4, tnx = tl&15;
    float acc[16] = {};
    const float* W = edge_w1 + (g ? 4096 : 0);
    #pragma unroll 4
    for (int m=0;m<64;m++){
      float4 av = *(const float4*)&sHt[m*64 + 4*tjx];
      float4 bv = *(const float4*)&W  [m*64 + 4*tnx];
      fma4x4(acc, av, bv);
    }
    if (g==0){
      #pragma unroll
      for (int r=0;r<4;r++)
        #pragma unroll
        for (int c=0;c<4;c++)
          sAB[(4*tjx+r)*64 + 4*tnx+c] = acc[r*4+c] + sB1[4*tnx+c];
    } else {
      #pragma unroll
      for (int r=0;r<4;r++)
        #pragma unroll
        for (int c=0;c<4;c++)
          sC[(4*tjx+r)*72 + 4*tnx+c] = (__bf16)acc[r*4+c];
    }
  }
  __syncthreads();   // also fences sHt before sTr/sDsq overlay writes

  const int lg = lane>>4, ln = lane&15;

  // ---- main loop: wave wv owns node i = ib*8+wv; NO barriers ----
  for (int ib=0; ib<8; ib++){
    const int i = ib*8 + wv;
    {
      float dx=sPX[i]-sPX[lane], dy=sPY[i]-sPY[lane], dz=sPZ[i]-sPZ[lane];
      sDsq[wv*64+lane] = dx*dx+dy*dy+dz*dz;
    }
    float ab8[2][8];
    #pragma unroll
    for (int kb=0;kb<2;kb++){
      *(float4*)&ab8[kb][0] = *(const float4*)&sAB[i*64 + kb*32+lg*8];
      *(float4*)&ab8[kb][4] = *(const float4*)&sAB[i*64 + kb*32+lg*8+4];
    }
    float trs[2][8];
    #pragma unroll
    for (int kb=0;kb<2;kb++)
      #pragma unroll
      for (int e=0;e<8;e++) trs[kb][e]=0.f;

    float sw=0.f, swx=0.f, swy=0.f, swz=0.f;

    #pragma unroll
    for (int jt=0;jt<4;jt++){
      const int j = jt*16 + ln;
      const float dq = sDsq[wv*64+j];
      f32x4 a4[4];
      #pragma unroll
      for (int nt=0;nt<4;nt++) a4[nt] = f32x4{0.f,0.f,0.f,0.f};

      #pragma unroll
      for (int kb=0;kb<2;kb++){
        bf16x8 c8 = *(const bf16x8*)&sC[j*72 + kb*32 + lg*8];
        float w8[8];
        *(float4*)&w8[0] = *(const float4*)&sW1L[kb*32+lg*8];
        *(float4*)&w8[4] = *(const float4*)&sW1L[kb*32+lg*8+4];
        bf16x8 t8;
        #pragma unroll
        for (int e=0;e<8;e++){
          float v = ab8[kb][e] + (float)c8[e] + dq*w8[e];
          v = fmaxf(v, 0.f);
          trs[kb][e] += v;
          t8[e] = (__bf16)v;
        }
        #pragma unroll
        for (int nt=0;nt<4;nt++){
          bf16x8 b8 = *(const bf16x8*)&sW3t[(nt*16+ln)*72 + kb*32 + lg*8];
          a4[nt] = mfma16(t8, b8, a4[nt]);
        }
      }

      // epilogue slice: w_j = relu(U+cb1')·cw2, 16-lane butterfly
      float wr[4];
      #pragma unroll
      for (int r=0;r<4;r++){
        float p = 0.f;
        #pragma unroll
        for (int nt=0;nt<4;nt++){
          int n = nt*16 + ln;
          float u = a4[nt][r] + sCB1p[n];
          p += fmaxf(u, 0.f)*sCW2[n];
        }
        p += __shfl_xor(p,1); p += __shfl_xor(p,2);
        p += __shfl_xor(p,4); p += __shfl_xor(p,8);
        wr[r] = p;
      }
      #pragma unroll
      for (int r=0;r<4;r++){
        int jj = jt*16 + lg*4 + r;
        sw  += wr[r];
        swx += wr[r]*sPX[jj];
        swy += wr[r]*sPY[jj];
        swz += wr[r]*sPZ[jj];
      }
    }

    // Trow: butterfly over 16 j-lanes, 4 lanes store bf16x8
    #pragma unroll
    for (int kb=0;kb<2;kb++)
      #pragma unroll
      for (int e=0;e<8;e++){
        float s = trs[kb][e];
        s += __shfl_xor(s,1); s += __shfl_xor(s,2);
        s += __shfl_xor(s,4); s += __shfl_xor(s,8);
        trs[kb][e] = s;
      }
    if (ln == 0){
      #pragma unroll
      for (int kb=0;kb<2;kb++){
        bf16x8 t8;
        #pragma unroll
        for (int e=0;e<8;e++) t8[e] = (__bf16)trs[kb][e];
        *(bf16x8*)&sTr[i*72 + kb*32 + lg*8] = t8;
      }
    }

    sw  += __shfl_xor(sw,16);  sw  += __shfl_xor(sw,32);
    swx += __shfl_xor(swx,16); swx += __shfl_xor(swx,32);
    swy += __shfl_xor(swy,16); swy += __shfl_xor(swy,32);
    swz += __shfl_xor(swz,16); swz += __shfl_xor(swz,32);
    if (lane == 0){
      float* o = out + (bs*64 + i)*6;
      o[0] = sPX[i] + (sPX[i]*sw - swx)*(1.f/64.f);
      o[1] = sPY[i] + (sPY[i]*sw - swy)*(1.f/64.f);
      o[2] = sPZ[i] + (sPZ[i]*sw - swz)*(1.f/64.f);
    }
  }

  // ---- batched m_i = Trow@W2 + 64*b2 ----
  __syncthreads();
  #pragma unroll
  for (int t2=0;t2<2;t2++){
    int t  = wv*2 + t2;
    int it = t>>2, nt = t&3;
    f32x4 a2 = f32x4{0.f,0.f,0.f,0.f};
    #pragma unroll
    for (int kb=0;kb<2;kb++){
      bf16x8 a8 = *(const bf16x8*)&sTr [(it*16+ln)*72 + kb*32 + lg*8];
      bf16x8 b8 = *(const bf16x8*)&sW2t[(nt*16+ln)*72 + kb*32 + lg*8];
      a2 = mfma16(a8, b8, a2);
    }
    int n = nt*16 + ln;
    float b2n = 64.f*sB2[n];
    #pragma unroll
    for (int r=0;r<4;r++){
      int i = it*16 + lg*4 + r;
      ws_mi[(bs*64 + i)*64 + n] = a2[r] + b2n;
    }
  }
}

// Node kernel: z = relu([h|mi]@nw1+nb1) via MFMA (K=128);
// vel_out = vel + h@fw3 + z@(nw2@fw3) + (nb2@fw3 + fb3).
__global__ __launch_bounds__(256)
void egnn_node_mfma(const float* __restrict__ x,
    const float* __restrict__ emb_w,  const float* __restrict__ emb_b,
    const float* __restrict__ node_w1,const float* __restrict__ node_b1,
    const float* __restrict__ node_w2,const float* __restrict__ node_b2,
    const float* __restrict__ final_w,const float* __restrict__ final_b,
    float* __restrict__ out, const float* __restrict__ ws_mi)
{
  __shared__ __align__(16) float  sHt [64*64];    // h^T [m][j] f32
  __shared__ __align__(16) __bf16 sAb [64*136];   // A rows: [j][ h(0:64) | mi(64:128) ]
  __shared__ __align__(16) __bf16 sNW1t[64*136];  // nw1^T [n][kk]
  __shared__ __align__(16) float sNW2[64*64];
  __shared__ float sG  [64*4];   // (nw2@fw3)[k][d]
  __shared__ float sHf3[64*4];   // (h@fw3)[j][d]
  __shared__ float sFW3[64*4];   // fw[:,3:6]
  __shared__ float sCvec[4];
  __shared__ float sXL[384], sEW[384], sEB[64], sNB1[64], sNB2[64];

  const int bs=blockIdx.x, tid=threadIdx.x;
  const int lane=tid&63, wv=tid>>6, ln=lane&15, lg=lane>>4;
  const float* xg = x + bs*384;

  for (int q=tid;q<384;q+=256){ sXL[q]=xg[q]; sEW[q]=emb_w[q]; }
  if (tid<64){ sEB[tid]=emb_b[tid]; sNB1[tid]=node_b1[tid]; sNB2[tid]=node_b2[tid]; }
  if (tid<192){ int n=tid&63, d=tid>>6; sFW3[n*4+d]=final_w[n*6+3+d]; }
  { const float4* g2=(const float4*)node_w2; float4* d2=(float4*)sNW2;
    #pragma unroll
    for (int e=0;e<4;e++) d2[tid+e*256]=g2[tid+e*256]; }
  #pragma unroll
  for (int e=0;e<32;e++){ int idx=tid+e*256; int kk=idx>>6, n=idx&63;
    sNW1t[n*136+kk]=(__bf16)node_w1[idx]; }
  { const float* mig = ws_mi + bs*4096;
    #pragma unroll
    for (int e=0;e<16;e++){ int idx=tid+e*256; int i=idx>>6, n=idx&63;
      sAb[i*136+64+n]=(__bf16)mig[idx]; } }
  __syncthreads();

  // h: thread (j, 16 m's) -> sHt f32 + sAb bf16
  { int j=tid&63, mb=tid>>6;
    #pragma unroll
    for (int mm=0;mm<16;mm++){ int m=mb*16+mm;
      float v=sEB[m];
      #pragma unroll
      for (int d=0;d<6;d++) v+=sXL[j*6+d]*sEW[d*64+m];
      sHt[m*64+j]=v; sAb[j*136+m]=(__bf16)v; } }
  __syncthreads();

  // G = nw2@fw3 (skewed n to dodge bank conflicts), hf3 = h@fw3, cvec
  if (tid<192){
    int k=tid&63, d=tid>>6;
    float gacc=0.f, s=0.f;
    for (int nn=0;nn<64;nn++){
      int n=(nn+k)&63;
      gacc += sNW2[k*64+n]*sFW3[n*4+d];
      s    += sHt[nn*64+k]*sFW3[nn*4+d];
    }
    sG[k*4+d]=gacc; sHf3[k*4+d]=s;
  } else if (tid<195){
    int d=tid-192; float c=final_b[3+d];
    for (int n=0;n<64;n++) c+=sNB2[n]*sFW3[n*4+d];
    sCvec[d]=c;
  }
  __syncthreads();

  // z GEMM: wave wv owns 16-row j-tile, K=128, N=64
  f32x4 acc[4];
  #pragma unroll
  for (int nt=0;nt<4;nt++) acc[nt]=f32x4{0.f,0.f,0.f,0.f};
  #pragma unroll
  for (int kb=0;kb<4;kb++){
    bf16x8 a8 = *(const bf16x8*)&sAb[(wv*16+ln)*136 + kb*32 + lg*8];
    #pragma unroll
    for (int nt=0;nt<4;nt++){
      bf16x8 b8 = *(const bf16x8*)&sNW1t[(nt*16+ln)*136 + kb*32 + lg*8];
      acc[nt]=mfma16(a8,b8,acc[nt]);
    }
  }
  // vel epilogue: p[r][d] = sum_n relu(z)*G[n][d], butterfly over 16 n-lanes
  float p[4][3];
  #pragma unroll
  for(int r=0;r<4;r++){ p[r][0]=0.f; p[r][1]=0.f; p[r][2]=0.f; }
  #pragma unroll
  for (int nt=0;nt<4;nt++){
    int n=nt*16+ln;
    float zb=sNB1[n];
    float g0=sG[n*4], g1=sG[n*4+1], g2=sG[n*4+2];
    #pragma unroll
    for (int r=0;r<4;r++){
      float u=fmaxf(acc[nt][r]+zb,0.f);
      p[r][0]+=u*g0; p[r][1]+=u*g1; p[r][2]+=u*g2;
    }
  }
  #pragma unroll
  for (int off=1;off<16;off<<=1)
    #pragma unroll
    for (int r=0;r<4;r++){
      p[r][0]+=__shfl_xor(p[r][0],off);
      p[r][1]+=__shfl_xor(p[r][1],off);
      p[r][2]+=__shfl_xor(p[r][2],off);
    }
  if (ln==0){
    #pragma unroll
    for (int r=0;r<4;r++){
      int j=wv*16+lg*4+r; int base=(bs*64+j)*6;
      #pragma unroll
      for (int d=0;d<3;d++)
        out[base+3+d]=xg[j*6+3+d]+sHf3[j*4+d]+sCvec[d]+p[r][d];
    }
  }
}

extern "C" void kernel_launch(void* const* d_in, const int* in_sizes, int n_in,
                              void* d_out, int out_size, void* d_ws, size_t ws_size,
                              hipStream_t stream)
{
  const float* x        = (const float*)d_in[0];
  const float* emb_w    = (const float*)d_in[1];
  const float* emb_b    = (const float*)d_in[2];
  const float* edge_w1  = (const float*)d_in[3];
  const float* edge_b1  = (const float*)d_in[4];
  const float* edge_w2  = (const float*)d_in[5];
  const float* edge_b2  = (const float*)d_in[6];
  const float* node_w1  = (const float*)d_in[7];
  const float* node_b1  = (const float*)d_in[8];
  const float* node_w2  = (const float*)d_in[9];
  const float* node_b2  = (const float*)d_in[10];
  const float* coord_w1 = (const float*)d_in[11];
  const float* coord_b1 = (const float*)d_in[12];
  const float* coord_w2 = (const float*)d_in[13];
  const float* final_w  = (const float*)d_in[14];
  const float* final_b  = (const float*)d_in[15];
  float* out   = (float*)d_out;
  float* ws_mi = (float*)d_ws;   // 256*64*64 f32 = 4 MB

  egnn_edge_mfma<<<NG, 512, 0, stream>>>(x, emb_w, emb_b,
      edge_w1, edge_b1, edge_w2, edge_b2, coord_w1, coord_b1, coord_w2,
      out, ws_mi);
  egnn_node_mfma<<<NG, 256, 0, stream>>>(x, emb_w, emb_b,
      node_w1, node_b1, node_w2, node_b2, final_w, final_b,
      out, ws_mi);
}